// Round 8
// baseline (95.467 us; speedup 1.0000x reference)
//
#include <hip/hip_runtime.h>

#define NBODY 8192
#define BLOCK 256
#define IPT 4                       // i-bodies per thread
#define ITILE (BLOCK * IPT)         // 1024
#define NITILES (NBODY / ITILE)     // 8
#define SLABS 128                   // j-slabs
#define JCHUNK (NBODY / SLABS)      // 64
#define PHASE 8                     // j-bodies register-hoisted per burst
#define NPHASE (JCHUNK / PHASE)     // 8
#define SOFT2 1.0e-4f               // 0.01^2

// R7 A/B (NR-rsqrt: +12 ops/pair -> +9.9us, exactly the 2cy/op issue model):
// kernel is VALU-ISSUE-BOUND and v_rsq is ~free on the trans pipe. So this
// round cuts issue slots/pair and consolidates proven pieces:
//  - R0 single-kernel direct-atomic structure (best dur 78.7; partials+reduce
//    cost +4-7us in R2/R4)
//  - R4 burst-hoist (-3us proven A/B)
//  - quadratic expansion: r2 = (|pi|^2+eps) + |pj|^2 - 2 pi.pj and
//    a_i = sum(w p_j) - (sum w) p_i. Staging (-2x,-2y,-2z,-m/2) and |pj|^2
//    drops the 3 subs: 11 slots/pair vs 12, displacement never materialized.
//    Self-pair contributes exactly 0; cancellation err ~4e-7 << eps=1e-4.
__global__ __launch_bounds__(BLOCK, 4) void force_kernel(
    const float* __restrict__ pos, const float* __restrict__ mass,
    float* __restrict__ out) {
  __shared__ float4 tile[JCHUNK];  // (-2x, -2y, -2z, -m/2)
  __shared__ float jn[JCHUNK];     // |pj|^2

  const int t = threadIdx.x;
  if (t < JCHUNK) {
    const int j = blockIdx.y * JCHUNK + t;
    const float jx = pos[j * 3 + 0];
    const float jy = pos[j * 3 + 1];
    const float jz = pos[j * 3 + 2];
    tile[t] = make_float4(-2.f * jx, -2.f * jy, -2.f * jz, -0.5f * mass[j]);
    jn[t] = fmaf(jx, jx, fmaf(jy, jy, jz * jz));
  }

  const int ib = blockIdx.x * ITILE + t;  // i-bodies: ib + p*BLOCK
  float xi[IPT], yi[IPT], zi[IPT], ni[IPT];
  float ax[IPT], ay[IPT], az[IPT], sw[IPT];
#pragma unroll
  for (int p = 0; p < IPT; ++p) {
    const int i = ib + p * BLOCK;
    xi[p] = pos[i * 3 + 0];
    yi[p] = pos[i * 3 + 1];
    zi[p] = pos[i * 3 + 2];
    ni[p] = fmaf(xi[p], xi[p],
                 fmaf(yi[p], yi[p], fmaf(zi[p], zi[p], SOFT2)));
    ax[p] = 0.f; ay[p] = 0.f; az[p] = 0.f; sw[p] = 0.f;
  }

  __syncthreads();

  for (int c = 0; c < NPHASE; ++c) {
    // Burst-hoist 8 j-bodies (8 ds_read_b128 + 8 ds_read_b32, one wait).
    float4 jt[PHASE];
    float jv[PHASE];
#pragma unroll
    for (int u = 0; u < PHASE; ++u) {
      jt[u] = tile[c * PHASE + u];
      jv[u] = jn[c * PHASE + u];
    }

    // 11 full-rate slots per pair, rsq on the trans pipe:
    //   1 add (jn+ni), 3 fma (dot -> r2), 3 mul (W), 3 fma (acc), 1 add (sw)
#pragma unroll
    for (int u = 0; u < PHASE; ++u) {
#pragma unroll
      for (int p = 0; p < IPT; ++p) {
        float r2 = fmaf(jt[u].x, xi[p],
                   fmaf(jt[u].y, yi[p],
                   fmaf(jt[u].z, zi[p], jv[u] + ni[p])));
        float y = __builtin_amdgcn_rsqf(r2);   // v_rsq_f32, ~free (R7)
        float W = jt[u].w * ((y * y) * y);     // -m_j/2 * r^-3
        ax[p] = fmaf(W, jt[u].x, ax[p]);       // accumulates +m_j r^-3 x_j
        ay[p] = fmaf(W, jt[u].y, ay[p]);
        az[p] = fmaf(W, jt[u].z, az[p]);
        sw[p] += W;                            // -(1/2) sum m_j r^-3
      }
    }
  }

  // A_i = sum(w p_j) - (sum w) p_i = ax + 2*sw*xi ; then R0-proven atomics
  // (128-way contention, L2-side float adds, cheap).
#pragma unroll
  for (int p = 0; p < IPT; ++p) {
    const int i = ib + p * BLOCK;
    const float s2 = sw[p] + sw[p];
    atomicAdd(&out[i * 3 + 0], fmaf(s2, xi[p], ax[p]));
    atomicAdd(&out[i * 3 + 1], fmaf(s2, yi[p], ay[p]));
    atomicAdd(&out[i * 3 + 2], fmaf(s2, zi[p], az[p]));
  }
}

extern "C" void kernel_launch(void* const* d_in, const int* in_sizes, int n_in,
                              void* d_out, int out_size, void* d_ws,
                              size_t ws_size, hipStream_t stream) {
  const float* pos = (const float*)d_in[0];
  const float* mass = (const float*)d_in[1];
  float* out = (float*)d_out;

  // d_out is re-poisoned to 0xAA before every launch; atomics need zeros.
  hipMemsetAsync(d_out, 0, (size_t)out_size * sizeof(float), stream);

  force_kernel<<<dim3(NITILES, SLABS), BLOCK, 0, stream>>>(pos, mass, out);
}

// Round 9
// 78.195 us; speedup vs baseline: 1.2209x; 1.2209x over previous
//
#include <hip/hip_runtime.h>

#define NBODY 8192
#define BLOCK 256
#define SLABS 32
#define JCHUNK (NBODY / SLABS)   // 256 j-bodies per block
#define PHASE 16                 // j-bodies register-hoisted per burst
#define NPHASE (JCHUNK / PHASE)  // 16
#define SOFT2 1.0e-4f            // 0.01^2

// Consolidated best-of-session configuration:
//  - R0 single-kernel structure: IPT=1, grid (32,32)=1024 blocks, direct
//    atomics at 32-way contention (R8 measured: contention grows with
//    SLABS=32*IPT; 128-way cost +8us -> IPT=1 is the atomic sweet spot).
//  - R4's burst-hoist (-3us A/B): 16 float4 j-bodies LDS->VGPR per burst,
//    one lgkm wait per 16 reads instead of per unroll group.
//  - Classic 12-op pair form + v_rsq (R7 A/B: v_rsq is ~free on the trans
//    pipe; NR-software-rsqrt billed +10us at exactly the 2cy/op issue rate).
//  - Quadratic expansion reverted (R8: absmax 4->16 for ~1us — bad trade).
__global__ __launch_bounds__(BLOCK, 4) void nbody_kernel(
    const float* __restrict__ pos, const float* __restrict__ mass,
    float* __restrict__ out) {
  __shared__ float4 tile[JCHUNK];

  const int t = threadIdx.x;
  const int i = blockIdx.x * BLOCK + t;
  const int j = blockIdx.y * JCHUNK + t;

  // Stage j-slab (JCHUNK == BLOCK: one float4 per thread).
  tile[t] = make_float4(pos[j * 3 + 0], pos[j * 3 + 1], pos[j * 3 + 2],
                        mass[j]);

  const float xi = pos[i * 3 + 0];
  const float yi = pos[i * 3 + 1];
  const float zi = pos[i * 3 + 2];

  __syncthreads();

  float ax = 0.f, ay = 0.f, az = 0.f;

  for (int c = 0; c < NPHASE; ++c) {
    // Burst-hoist one phase of j-bodies into registers (64 VGPR): 16
    // independent wave-uniform ds_read_b128, single wait.
    float4 jt[PHASE];
#pragma unroll
    for (int u = 0; u < PHASE; ++u) jt[u] = tile[c * PHASE + u];

    // Pure-register compute: 12 full-rate ops + 1 trans per pair.
#pragma unroll
    for (int u = 0; u < PHASE; ++u) {
      float dx = jt[u].x - xi;
      float dy = jt[u].y - yi;
      float dz = jt[u].z - zi;
      float r2 = fmaf(dx, dx, fmaf(dy, dy, fmaf(dz, dz, SOFT2)));
      float inv = __builtin_amdgcn_rsqf(r2);   // v_rsq_f32
      float w = jt[u].w * ((inv * inv) * inv); // m_j * r^-3
      ax = fmaf(w, dx, ax);
      ay = fmaf(w, dy, ay);
      az = fmaf(w, dz, az);
    }
  }

  // 32 slabs contend per address (R0-proven; L2-side float adds).
  atomicAdd(&out[i * 3 + 0], ax);
  atomicAdd(&out[i * 3 + 1], ay);
  atomicAdd(&out[i * 3 + 2], az);
}

extern "C" void kernel_launch(void* const* d_in, const int* in_sizes, int n_in,
                              void* d_out, int out_size, void* d_ws,
                              size_t ws_size, hipStream_t stream) {
  const float* pos = (const float*)d_in[0];
  const float* mass = (const float*)d_in[1];
  float* out = (float*)d_out;

  // d_out is re-poisoned to 0xAA before every launch; atomics need zeros.
  hipMemsetAsync(d_out, 0, (size_t)out_size * sizeof(float), stream);

  nbody_kernel<<<dim3(NBODY / BLOCK, SLABS), BLOCK, 0, stream>>>(pos, mass,
                                                                 out);
}